// Round 1
// baseline (99.857 us; speedup 1.0000x reference)
//
#include <hip/hip_runtime.h>
#include <hip/hip_bf16.h>

// out[row] = dot(link[row*128 .. +128], theta[0..128)) for row in [0, 1M)
// Memory-bound: 512 MB read / 4 MB write per call. Strategy: 32 lanes x float4
// per row (fully coalesced 1 KiB/wave/instruction), shfl_xor reduce, theta
// float4 preloaded per-lane (lane's k-chunk is loop-invariant).

__global__ __launch_bounds__(256) void linmodel_dot_kernel(
    const float* __restrict__ link,
    const float* __restrict__ theta,
    float* __restrict__ out,
    int num_rows)
{
    const int lane = threadIdx.x & 63;
    const int sub  = lane & 31;   // k-chunk index within row (float4 granularity)
    const int half = lane >> 5;   // which row of the pair this half-wave handles

    const int waveInBlock   = threadIdx.x >> 6;
    const int wavesPerBlock = blockDim.x >> 6;
    const int gwave  = blockIdx.x * wavesPerBlock + waveInBlock;
    const int nwaves = gridDim.x * wavesPerBlock;

    // theta is 128 floats; this lane always dots against chunk `sub`.
    const float4 th = reinterpret_cast<const float4*>(theta)[sub];

    const int num_pairs = num_rows >> 1;  // 2 rows per wave per iteration

    for (int pair = gwave; pair < num_pairs; pair += nwaves) {
        const size_t row = (size_t)pair * 2 + half;
        const float4 a = reinterpret_cast<const float4*>(link + row * 128)[sub];

        float p = a.x * th.x + a.y * th.y + a.z * th.z + a.w * th.w;

        // Reduce across the 32 lanes of this half-wave (bits 0..4 only,
        // so the two halves stay independent).
        p += __shfl_xor(p, 1);
        p += __shfl_xor(p, 2);
        p += __shfl_xor(p, 4);
        p += __shfl_xor(p, 8);
        p += __shfl_xor(p, 16);

        if (sub == 0) out[row] = p;
    }
}

extern "C" void kernel_launch(void* const* d_in, const int* in_sizes, int n_in,
                              void* d_out, int out_size, void* d_ws, size_t ws_size,
                              hipStream_t stream) {
    const float* link  = (const float*)d_in[0];   // (1024, 1024, 128) f32
    // d_in[1]: route_features — unused by the forward pass
    const float* theta = (const float*)d_in[2];   // (128,) f32
    float* out = (float*)d_out;                   // (1024, 1024) f32

    const int num_rows = out_size;                // 1024*1024

    const int block = 256;
    const int grid  = 2048;  // 8192 waves, grid-stride over 524288 row-pairs
    linmodel_dot_kernel<<<grid, block, 0, stream>>>(link, theta, out, num_rows);
}